// Round 10
// baseline (364.468 us; speedup 1.0000x reference)
//
#include <hip/hip_runtime.h>

#define NELEM 500000
#define NDOF 500000
#define NNODE 250000
#define HID 64
#define NT 31250                 // wave-tiles: 2M GP-rows / 64 (exact)
#define NBLK 1024                // 4 blocks/CU * 256 CU
#define NWAVE (NBLK * 4)
#define CSTRIDE 262144           // u64 slots per per-XCD copy (2MB, pow2)

typedef _Float16 half2v __attribute__((ext_vector_type(2)));
typedef _Float16 half8v __attribute__((ext_vector_type(8)));
typedef float float4v __attribute__((ext_vector_type(4)));

// lambda = 2*log2(e): prescaled into W1,b1,W2,b2 so tanh needs no multiply.
#define LAM 2.885390081777927f
// fixed-point scale for the u64 packed atomic accumulate (range +-512,
// resolution 2.4e-7; lo->hi carry pollution <= ~16*2^-22 ~ 4e-6 << 0.0625)
#define FSCALE 4194304.0f        // 2^22
#define FINV   2.384185791015625e-7f

__device__ __forceinline__ half2v pk(float a, float b) {
    return __builtin_bit_cast(half2v, __builtin_amdgcn_cvt_pkrtz(a, b));
}
// tanh(z) with y = LAM*z prescaled. exp2(+-inf) saturates correctly.
__device__ __forceinline__ float tanh2(float y) {
    float e = __builtin_amdgcn_exp2f(y);
    float r = __builtin_amdgcn_rcpf(e + 1.0f);
    return fmaf(-2.0f, r, 1.0f);
}
__device__ __forceinline__ float fdot2(half2v a, half2v b, float c) {
    return __builtin_amdgcn_fdot2(a, b, c, false);
}

// ds_swizzle BitMode: src = ((lane&AND)|OR)^XOR within 32-lane halves.
//   quad broadcast j: 0x1C,0x3C,0x5C,0x7C ; xor16: 0x401F
#define SWZF(x, pat) __builtin_bit_cast(float, \
    __builtin_amdgcn_ds_swizzle(__builtin_bit_cast(int, (x)), (pat)))

// ---- setup kernel 1: pack per-lane W2 MFMA fragments into workspace ----
__global__ __launch_bounds__(64, 1) void pack_weights(
    const float* __restrict__ W2, uint4* __restrict__ ws)
{
    const int lane = threadIdx.x & 63;
    const int quad = lane >> 4, l15 = lane & 15;
#pragma unroll
    for (int t = 0; t < 4; t++)
#pragma unroll
        for (int f = 0; f < 2; f++) {
            union { uint4 q; uint u[4]; } T;
#pragma unroll
            for (int jj = 0; jj < 4; jj++) {
                const int k0 = f * 32 + quad * 8 + 2 * jj;
                const int n  = t * 16 + l15;
                T.u[jj] = __builtin_bit_cast(uint,
                    pk(LAM * W2[k0 * HID + n], LAM * W2[(k0 + 1) * HID + n]));
            }
            ws[(8 + 2 * t + f) * 64 + lane] = T.q;
        }
}

// ---- setup kernel 2: u1 = weight1 * u ----
__global__ __launch_bounds__(256, 8) void premul_u(
    const float* __restrict__ u, const float* __restrict__ w1,
    float* __restrict__ u1)
{
    const int i = blockIdx.x * 256 + threadIdx.x;
    if (i < NDOF / 4) {
        const float4 a = ((const float4*)u)[i];
        const float4 b = ((const float4*)w1)[i];
        ((float4*)u1)[i] = make_float4(a.x * b.x, a.y * b.y, a.z * b.z, a.w * b.w);
    }
}

// ---- epilogue: sum 8 per-XCD u64 copies, fixed-point -> 2x f32 ----
__global__ __launch_bounds__(256, 8) void convert_F(
    unsigned long long* __restrict__ F64,
    const unsigned long long* __restrict__ F8, const int priv)
{
    const int i = blockIdx.x * 256 + threadIdx.x;
    if (i < NNODE) {
        unsigned long long v;
        if (priv) {
            v = 0ull;
#pragma unroll
            for (int x = 0; x < 8; x++) v += F8[(size_t)x * CSTRIDE + i];
        } else {
            v = F64[i];
        }
        const int lo = (int)(unsigned)(v & 0xFFFFFFFFull);
        const int hi = (int)(unsigned)(v >> 32);
        *(float2*)&F64[i] = make_float2((float)lo * FINV, (float)hi * FINV);
    }
}

// one layer-2/3 tile step: C=b2 -> 2 MFMA -> tanh -> packed layer-3 partials
#define TSTEP(tt, qa, qb) do { \
    const float4v b2v = *(const float4v*)&b2t[wb + (tt) * 4]; \
    union { uint4 q; uint u[4]; } w3u; \
    w3u.q = *(const uint4*)&w3t[wb + (tt) * 4]; \
    float4v c = b2v; \
    c = __builtin_amdgcn_mfma_f32_16x16x32_f16(__builtin_bit_cast(half8v, (qa)), B0.v, c, 0, 0, 0); \
    c = __builtin_amdgcn_mfma_f32_16x16x32_f16(__builtin_bit_cast(half8v, (qb)), B1.v, c, 0, 0, 0); \
    _Pragma("unroll") \
    for (int reg = 0; reg < 4; reg++) { \
        const float h = tanh2(c[reg]); \
        const half2v hh = pk(h, h); \
        sp = sp + hh * __builtin_bit_cast(half2v, w3u.u[reg]); \
    } \
} while (0)

// r8 compute, byte-identical. Phase 3: per-XCD private copy (physical
// HW_REG_XCC_ID partition) via inline-asm global_atomic_add_x2 with NO
// sc bits -> executes at the LOCAL XCD L2 (gfx9 cache-policy model),
// sidestepping the ~18G ops/s coherence-point wall isolated in r7->r8.
// Correct because each copy's lines are only ever dirty in ONE L2 and
// the dispatch-end writeback precedes convert_F. Fallback (ws too
// small) = exact r8 path, TAGGED with 8KB dummy dynamic LDS so the
// counter table (LDS_Block_Size) records which path ran.
__global__ __launch_bounds__(256, 4) void fem_force_kernel(
    const float* __restrict__ u, const float* __restrict__ B,
    const float* __restrict__ Jacc, const float* __restrict__ gp_w,
    const int* __restrict__ conn, const float* __restrict__ weight1,
    const float* __restrict__ scales_inp, const float* __restrict__ limits_inp,
    const float* __restrict__ scales_grad, const float* __restrict__ limits_grad,
    const float* __restrict__ W1, const float* __restrict__ b1,
    const float* __restrict__ b2, const float* __restrict__ W3,
    const float* __restrict__ b3, const uint4* __restrict__ wt,
    const int premul, const int priv,
    unsigned long long* __restrict__ F64,
    unsigned long long* __restrict__ F8)
{
    extern __shared__ uint dynpad[];     // fallback path marker (unused)
    __shared__ uint sPQ[8 * 260];        // plane j at j*260 + wv*65 + row
    __shared__ uint sXs[4][64];          // per-wave packed (x0,x1)
    __shared__ uint sGs[4][64];          // per-wave packed (p,q)
    __shared__ __align__(16) float b2t[64];
    __shared__ __align__(16) uint  w3t[64];      // pk(W3[2n], W3[2n+1])
    __shared__ __align__(16) uint  w1tb[4][16];  // per-quad LAM*W1 pairs
    __shared__ __align__(16) float b1tb[4][16];  // per-quad LAM*b1

    const int tid  = threadIdx.x;
    const int lane = tid & 63;
    const int wv   = tid >> 6;
    const int quad = lane >> 4;
    const int l15  = lane & 15;
    const int g    = lane & 3;           // gauss point of this thread
    const int pqb  = wv * 65;            // this wave's sPQ row base

    // physical die id of this wave (never migrates) -> private copy index
    uint xcc;
    asm volatile("s_getreg_b32 %0, hwreg(HW_REG_XCC_ID)" : "=s"(xcc));
    unsigned long long* Fp = F8 + (size_t)(xcc & 7) * CSTRIDE;

    // block-shared tables (one copy), single barrier before the loop
    if (tid < 64) {
        const int i  = tid;
        const int it = (i >> 2) & 3, iq = i >> 4, ir = i & 3;
        const int n  = it * 16 + iq * 4 + ir;
        b2t[i] = LAM * b2[n];
        w3t[i] = __builtin_bit_cast(uint, pk(W3[2 * n], W3[2 * n + 1]));
    } else if (tid < 128) {
        const int i = tid - 64;          // i = q*16 + idx
        const int q = i >> 4, idx = i & 15, f = idx >> 3, jj = idx & 7;
        const int k = f * 32 + q * 8 + jj;
        w1tb[q][idx] = __builtin_bit_cast(uint, pk(LAM * W1[k], LAM * W1[HID + k]));
    } else if (tid < 192) {
        const int i = tid - 128;
        const int q = i >> 4, idx = i & 15, f = idx >> 3, jj = idx & 7;
        const int k = f * 32 + q * 8 + jj;
        b1tb[q][idx] = LAM * b1[k];
    }
    __syncthreads();

    const float SQ23 = 0.816496580927726f;
    const float si0 = scales_inp[0], si1 = scales_inp[1];
    const float li0 = limits_inp[0], li1 = limits_inp[1];
    const float isg0 = 1.0f / scales_grad[0], isg1 = 1.0f / scales_grad[1];
    const float b30c = b3[0] - limits_grad[0];
    const float b31c = b3[1] - limits_grad[1];
    const float gw  = gp_w[g];

    // ---- held W2 fragments: loaded ONCE, pinned (r5-proven) ----
    uint4 bfq[8];
#pragma unroll
    for (int i = 0; i < 8; i++) bfq[i] = wt[(8 + i) * 64 + lane];
#pragma unroll
    for (int i = 0; i < 8; i++)
        asm volatile("" : "+v"(bfq[i].x), "+v"(bfq[i].y), "+v"(bfq[i].z), "+v"(bfq[i].w));

    // ---- prologue: B + conn + u/Jacc for tile 0 ----
    int T = blockIdx.x * 4 + wv;
    float4 bq0, bq1, bq2, bq3, bq4, bq5;
    {
        const float4* Bp = (const float4*)(B + (size_t)T * 1536 + lane * 24);
        bq0 = Bp[0]; bq1 = Bp[1]; bq2 = Bp[2];
        bq3 = Bp[3]; bq4 = Bp[4]; bq5 = Bp[5];
    }
    int connT = conn[T * 64 + lane];
    float jacT = Jacc[T * 64 + lane];
    float2 uT = *(const float2*)(u + 2 * connT);
    float2 wvT = make_float2(1.f, 1.f);
    if (!premul) wvT = *(const float2*)(weight1 + 2 * connT);

    int connN = 0;
    float2 uN = make_float2(0.f, 0.f), wvN = make_float2(1.f, 1.f);
    float jacN = 0.f;

#pragma unroll 1
    for (; T < NT; T += NWAVE) {
        const int Tn = T + NWAVE;
        const bool hasN = (Tn < NT);
        // prefetch next conn/Jacc (independent loads; land during phase 1)
        if (hasN) {
            connN = conn[Tn * 64 + lane];
            jacN  = Jacc[Tn * 64 + lane];
        }

        // ---- phase 1: strain invariants -> P,Q planes + x ----
        {
            const float vx = wvT.x * uT.x, vy = wvT.y * uT.y;
            float ue[8];
            ue[0] = SWZF(vx, 0x1C); ue[1] = SWZF(vy, 0x1C);
            ue[2] = SWZF(vx, 0x3C); ue[3] = SWZF(vy, 0x3C);
            ue[4] = SWZF(vx, 0x5C); ue[5] = SWZF(vy, 0x5C);
            ue[6] = SWZF(vx, 0x7C); ue[7] = SWZF(vy, 0x7C);

            float Bg[24];
            Bg[0]=bq0.x; Bg[1]=bq0.y; Bg[2]=bq0.z; Bg[3]=bq0.w;
            Bg[4]=bq1.x; Bg[5]=bq1.y; Bg[6]=bq1.z; Bg[7]=bq1.w;
            Bg[8]=bq2.x; Bg[9]=bq2.y; Bg[10]=bq2.z; Bg[11]=bq2.w;
            Bg[12]=bq3.x; Bg[13]=bq3.y; Bg[14]=bq3.z; Bg[15]=bq3.w;
            Bg[16]=bq4.x; Bg[17]=bq4.y; Bg[18]=bq4.z; Bg[19]=bq4.w;
            Bg[20]=bq5.x; Bg[21]=bq5.y; Bg[22]=bq5.z; Bg[23]=bq5.w;

            float s0 = 0.f, s1 = 0.f, s2 = 0.f;
#pragma unroll
            for (int j = 0; j < 8; j++) {
                s0 = fmaf(Bg[j],      ue[j], s0);
                s1 = fmaf(Bg[8 + j],  ue[j], s1);
                s2 = fmaf(Bg[16 + j], ue[j], s2);
            }
            const float ev  = s0 + s1;
            const float ev3 = ev * (1.0f / 3.0f);
            const float d00 = s0 - ev3, d11 = s1 - ev3, d22 = -ev3, d01 = 0.5f * s2;
            const float det = sqrtf(d00 * d00 + d11 * d11 + d22 * d22 + 2.0f * d01 * d01);
            const float rd  = __builtin_amdgcn_rcpf(det);
            const float es  = det * SQ23;
            const float wgt = jacT * gw;
            const float sc  = SQ23 * rd * wgt;
            const float c00 = sc * d00, c11 = sc * d11, c01 = sc * d01;
#pragma unroll
            for (int j = 0; j < 8; j++) {
                const float P = wgt * (Bg[j] + Bg[8 + j]);
                const float Q = fmaf(c00, Bg[j], fmaf(c11, Bg[8 + j], c01 * Bg[16 + j]));
                sPQ[j * 260 + pqb + lane] = __builtin_bit_cast(uint, pk(P, Q));
            }
            sXs[wv][lane] = __builtin_bit_cast(uint,
                pk(fmaf(ev, si0, li0), fmaf(es, si1, li1)));
        }
        // reload B regs for next tile (consumed above; land during phase 2)
        if (hasN) {
            const float4* Bp = (const float4*)(B + (size_t)Tn * 1536 + lane * 24);
            bq0 = Bp[0]; bq1 = Bp[1]; bq2 = Bp[2];
            bq3 = Bp[3]; bq4 = Bp[4]; bq5 = Bp[5];
        }
        asm volatile("s_waitcnt lgkmcnt(0)");
        __builtin_amdgcn_sched_barrier(0);
        // prefetch next u/weight1 (connN landed during phase 1)
        if (hasN) {
            uN = *(const float2*)(u + 2 * connN);
            if (!premul) wvN = *(const float2*)(weight1 + 2 * connN);
        }

        // ---- phase 2: wave-level MFMA MLP over this wave's 64 rows ----
        int zr = 0;                  // opaque zero: keeps table reads in-loop
#pragma unroll 1
        for (int rt = 0; rt < 4; rt++) {
            asm volatile("" : "+v"(zr));
            const int qz = quad + zr;
            const int wb = qz * 16;
            const half2v xp = __builtin_bit_cast(half2v, sXs[wv][rt * 16 + l15]);

            // layer-1 weights: quad-broadcast LDS reads (conflict-free)
            union { uint4 q[4]; uint u[16]; } W1L;
            union { float4 q[4]; float f[16]; } B1L;
#pragma unroll
            for (int i = 0; i < 4; i++) {
                W1L.q[i] = *(const uint4*)&w1tb[qz][4 * i];
                B1L.q[i] = *(const float4*)&b1tb[qz][4 * i];
            }

            union { half8v v; uint uu[4]; } B0, B1;
#pragma unroll
            for (int jj = 0; jj < 4; jj++) {
                const float t0 = tanh2(fdot2(xp, __builtin_bit_cast(half2v, W1L.u[2 * jj]),     B1L.f[2 * jj]));
                const float t1 = tanh2(fdot2(xp, __builtin_bit_cast(half2v, W1L.u[2 * jj + 1]), B1L.f[2 * jj + 1]));
                const float t2 = tanh2(fdot2(xp, __builtin_bit_cast(half2v, W1L.u[8 + 2 * jj]),     B1L.f[8 + 2 * jj]));
                const float t3 = tanh2(fdot2(xp, __builtin_bit_cast(half2v, W1L.u[8 + 2 * jj + 1]), B1L.f[8 + 2 * jj + 1]));
                B0.uu[jj] = __builtin_bit_cast(uint, pk(t0, t1));
                B1.uu[jj] = __builtin_bit_cast(uint, pk(t2, t3));
            }

            half2v sp = {_Float16(0.f), _Float16(0.f)};
            TSTEP(0, bfq[0], bfq[1]);
            TSTEP(1, bfq[2], bfq[3]);
            TSTEP(2, bfq[4], bfq[5]);
            TSTEP(3, bfq[6], bfq[7]);

            float s0 = (float)sp[0], s1 = (float)sp[1];
            s0 += SWZF(s0, 0x401F);
            s1 += SWZF(s1, 0x401F);
            s0 += __shfl_xor(s0, 32, 64);
            s1 += __shfl_xor(s1, 32, 64);
            if (quad == 0) {
                const float p = (s0 + b30c) * isg0;
                const float q = (s1 + b31c) * isg1;
                sGs[wv][rt * 16 + l15] = __builtin_bit_cast(uint, pk(p, q));
            }
        }
        // one drain per tile: B regs, uN and the PREVIOUS tile's atomics
        // are all >= one phase old here.
        asm volatile("s_waitcnt vmcnt(0) lgkmcnt(0)");
        __builtin_amdgcn_sched_barrier(0);

        // ---- phase 3: EP pair -> ONE u64 atomic per pair ----
        {
            const int rb = lane & ~3;
            const int j0 = 2 * g;
            float a = 0.f, b = 0.f;
#pragma unroll
            for (int gp = 0; gp < 4; gp++) {
                const int rr = rb + gp;
                const half2v pq = __builtin_bit_cast(half2v, sGs[wv][rr]);
                const uint w0 = sPQ[j0 * 260 + pqb + rr];
                const uint w1 = sPQ[(j0 + 1) * 260 + pqb + rr];
                a = fdot2(pq, __builtin_bit_cast(half2v, w0), a);
                b = fdot2(pq, __builtin_bit_cast(half2v, w1), b);
            }
            const int ia = __float2int_rn(a * FSCALE);
            const int ib = __float2int_rn(b * FSCALE);
            const unsigned long long pkd =
                ((unsigned long long)(unsigned)ib << 32) | (unsigned)ia;
            if (priv) {
                // no sc bits -> atomic executes at the LOCAL XCD L2
                // (copy is XCD-exclusive by the xcc partition)
                const unsigned long long a64 =
                    (unsigned long long)(Fp + connT);
                asm volatile("global_atomic_add_x2 %0, %1, off"
                             :: "v"(a64), "v"(pkd) : "memory");
            } else {
                atomicAdd(&F64[connT], pkd);
            }
        }

        connT = connN; uT = uN; jacT = jacN; wvT = wvN;
    }
}

extern "C" void kernel_launch(void* const* d_in, const int* in_sizes, int n_in,
                              void* d_out, int out_size, void* d_ws, size_t ws_size,
                              hipStream_t stream) {
    const float* u           = (const float*)d_in[0];
    const float* B           = (const float*)d_in[1];
    const float* Jacc        = (const float*)d_in[2];
    const float* gp_w        = (const float*)d_in[3];
    const int*   conn        = (const int*)  d_in[4];
    const float* weight1     = (const float*)d_in[5];
    const float* scales_inp  = (const float*)d_in[6];
    const float* limits_inp  = (const float*)d_in[7];
    const float* scales_grad = (const float*)d_in[8];
    const float* limits_grad = (const float*)d_in[9];
    const float* W1          = (const float*)d_in[10];
    const float* b1          = (const float*)d_in[11];
    const float* W2          = (const float*)d_in[12];
    const float* b2          = (const float*)d_in[13];
    const float* W3          = (const float*)d_in[14];
    const float* b3          = (const float*)d_in[15];
    unsigned long long* F64 = (unsigned long long*)d_out;

    const size_t priv_bytes = (size_t)8 * CSTRIDE * 8;   // 16 MB
    uint4* wt = (uint4*)d_ws;                            // 16 KB @ 0
    const int can_priv = (ws_size >= 16384 + priv_bytes) ? 1 : 0;

    unsigned long long* F8;
    float* u1;
    int can_premul;
    if (can_priv) {
        F8 = (unsigned long long*)((char*)d_ws + 16384);           // 16 MB
        u1 = (float*)((char*)d_ws + 16384 + priv_bytes);           // 2 MB
        can_premul = (ws_size >= 16384 + priv_bytes + sizeof(float) * NDOF) ? 1 : 0;
    } else {
        u1 = (float*)((char*)d_ws + 16384);
        F8 = (unsigned long long*)u1;    // unused (priv=0), valid pointer
        can_premul = (ws_size >= 16384 + sizeof(float) * NDOF) ? 1 : 0;
    }

    (void)hipMemsetAsync(d_out, 0, sizeof(float) * NDOF, stream);
    if (can_priv)
        (void)hipMemsetAsync(F8, 0, priv_bytes, stream);

    pack_weights<<<1, 64, 0, stream>>>(W2, wt);
    if (can_premul)
        premul_u<<<(NDOF / 4 + 255) / 256, 256, 0, stream>>>(u, weight1, u1);

    // fallback path carries an 8KB dummy dynamic-LDS tag so the rocprof
    // counter table (LDS_Block_Size) records which path actually ran.
    const size_t dyn_lds = can_priv ? 0 : 8192;
    fem_force_kernel<<<NBLK, 256, dyn_lds, stream>>>(
        can_premul ? u1 : u, B, Jacc, gp_w, conn, weight1,
        scales_inp, limits_inp, scales_grad, limits_grad,
        W1, b1, b2, W3, b3, wt, can_premul, can_priv, F64, F8);

    convert_F<<<(NNODE + 255) / 256, 256, 0, stream>>>(F64, F8, can_priv);
}

// Round 11
// 351.452 us; speedup vs baseline: 1.0370x; 1.0370x over previous
//
#include <hip/hip_runtime.h>

#define NELEM 500000
#define NDOF 500000
#define NNODE 250000
#define HID 64
#define NT 31250                 // wave-tiles: 2M GP-rows / 64 (exact)
#define NBLK 1024                // 4 blocks/CU * 256 CU
#define NWAVE (NBLK * 4)

typedef _Float16 half2v __attribute__((ext_vector_type(2)));
typedef _Float16 half8v __attribute__((ext_vector_type(8)));
typedef float float4v __attribute__((ext_vector_type(4)));

// lambda = 2*log2(e): prescaled into W1,b1,W2,b2 so tanh needs no multiply.
#define LAM 2.885390081777927f
// fixed-point scale for the u64 packed atomic accumulate (range +-512,
// resolution 2.4e-7; lo->hi carry pollution <= ~16*2^-22 ~ 4e-6 << 0.0625)
#define FSCALE 4194304.0f        // 2^22
#define FINV   2.384185791015625e-7f

__device__ __forceinline__ half2v pk(float a, float b) {
    return __builtin_bit_cast(half2v, __builtin_amdgcn_cvt_pkrtz(a, b));
}
// tanh(z) with y = LAM*z prescaled. exp2(+-inf) saturates correctly.
__device__ __forceinline__ float tanh2(float y) {
    float e = __builtin_amdgcn_exp2f(y);
    float r = __builtin_amdgcn_rcpf(e + 1.0f);
    return fmaf(-2.0f, r, 1.0f);
}
__device__ __forceinline__ float fdot2(half2v a, half2v b, float c) {
    return __builtin_amdgcn_fdot2(a, b, c, false);
}

// ds_swizzle BitMode: src = ((lane&AND)|OR)^XOR within 32-lane halves.
//   quad broadcast j: 0x1C,0x3C,0x5C,0x7C ; xor16: 0x401F
#define SWZF(x, pat) __builtin_bit_cast(float, \
    __builtin_amdgcn_ds_swizzle(__builtin_bit_cast(int, (x)), (pat)))

// ---- setup: block 0 packs W2 MFMA fragments; blocks 1+ do u1=w1*u ----
__global__ __launch_bounds__(256, 4) void setup_all(
    const float* __restrict__ W2, uint4* __restrict__ ws,
    const float* __restrict__ u, const float* __restrict__ w1,
    float* __restrict__ u1, const int premul)
{
    if (blockIdx.x == 0) {
        if (threadIdx.x < 64) {
            const int lane = threadIdx.x;
            const int quad = lane >> 4, l15 = lane & 15;
#pragma unroll
            for (int t = 0; t < 4; t++)
#pragma unroll
                for (int f = 0; f < 2; f++) {
                    union { uint4 q; uint u[4]; } T;
#pragma unroll
                    for (int jj = 0; jj < 4; jj++) {
                        const int k0 = f * 32 + quad * 8 + 2 * jj;
                        const int n  = t * 16 + l15;
                        T.u[jj] = __builtin_bit_cast(uint,
                            pk(LAM * W2[k0 * HID + n], LAM * W2[(k0 + 1) * HID + n]));
                    }
                    ws[(8 + 2 * t + f) * 64 + lane] = T.q;
                }
        }
    } else if (premul) {
        const int i = (blockIdx.x - 1) * 256 + threadIdx.x;
        if (i < NDOF / 4) {
            const float4 a = ((const float4*)u)[i];
            const float4 b = ((const float4*)w1)[i];
            ((float4*)u1)[i] = make_float4(a.x * b.x, a.y * b.y, a.z * b.z, a.w * b.w);
        }
    }
}

// ---- epilogue: in-place u64 fixed-point -> 2x f32 (one thread per node) ----
__global__ __launch_bounds__(256, 8) void convert_F(unsigned long long* __restrict__ F64)
{
    const int i = blockIdx.x * 256 + threadIdx.x;
    if (i < NNODE) {
        const unsigned long long v = F64[i];
        const int lo = (int)(unsigned)(v & 0xFFFFFFFFull);
        const int hi = (int)(unsigned)(v >> 32);
        *(float2*)&F64[i] = make_float2((float)lo * FINV, (float)hi * FINV);
    }
}

// one layer-2/3 tile step: C=b2 -> 2 MFMA -> tanh -> packed layer-3 partials
#define TSTEP(tt, qa, qb) do { \
    const float4v b2v = *(const float4v*)&b2t[wb + (tt) * 4]; \
    union { uint4 q; uint u[4]; } w3u; \
    w3u.q = *(const uint4*)&w3t[wb + (tt) * 4]; \
    float4v c = b2v; \
    c = __builtin_amdgcn_mfma_f32_16x16x32_f16(__builtin_bit_cast(half8v, (qa)), B0.v, c, 0, 0, 0); \
    c = __builtin_amdgcn_mfma_f32_16x16x32_f16(__builtin_bit_cast(half8v, (qb)), B1.v, c, 0, 0, 0); \
    _Pragma("unroll") \
    for (int reg = 0; reg < 4; reg++) { \
        const float h = tanh2(c[reg]); \
        const half2v hh = pk(h, h); \
        sp = sp + hh * __builtin_bit_cast(half2v, w3u.u[reg]); \
    } \
} while (0)

// r8 compute, with the phase-3 drain relaxed: only lgkmcnt(0) before the
// LDS-only phase 3 (r10 proved atomics cannot be moved off the memory-side
// coherence point; the 2M-op service floor ~110us stands). Removing the
// manual vmcnt(0) lets the compiler place counted vmcnt waits at phase-1's
// actual register uses, aging the prior tile's atomic one extra phase
// before any oldest-first wait can touch it.
__global__ __launch_bounds__(256, 4) void fem_force_kernel(
    const float* __restrict__ u, const float* __restrict__ B,
    const float* __restrict__ Jacc, const float* __restrict__ gp_w,
    const int* __restrict__ conn, const float* __restrict__ weight1,
    const float* __restrict__ scales_inp, const float* __restrict__ limits_inp,
    const float* __restrict__ scales_grad, const float* __restrict__ limits_grad,
    const float* __restrict__ W1, const float* __restrict__ b1,
    const float* __restrict__ b2, const float* __restrict__ W3,
    const float* __restrict__ b3, const uint4* __restrict__ wt,
    const int premul, unsigned long long* __restrict__ F64)
{
    __shared__ uint sPQ[8 * 260];        // plane j at j*260 + wv*65 + row
    __shared__ uint sXs[4][64];          // per-wave packed (x0,x1)
    __shared__ uint sGs[4][64];          // per-wave packed (p,q)
    __shared__ __align__(16) float b2t[64];
    __shared__ __align__(16) uint  w3t[64];      // pk(W3[2n], W3[2n+1])
    __shared__ __align__(16) uint  w1tb[4][16];  // per-quad LAM*W1 pairs
    __shared__ __align__(16) float b1tb[4][16];  // per-quad LAM*b1

    const int tid  = threadIdx.x;
    const int lane = tid & 63;
    const int wv   = tid >> 6;
    const int quad = lane >> 4;
    const int l15  = lane & 15;
    const int g    = lane & 3;           // gauss point of this thread
    const int pqb  = wv * 65;            // this wave's sPQ row base

    // block-shared tables (one copy), single barrier before the loop
    if (tid < 64) {
        const int i  = tid;
        const int it = (i >> 2) & 3, iq = i >> 4, ir = i & 3;
        const int n  = it * 16 + iq * 4 + ir;
        b2t[i] = LAM * b2[n];
        w3t[i] = __builtin_bit_cast(uint, pk(W3[2 * n], W3[2 * n + 1]));
    } else if (tid < 128) {
        const int i = tid - 64;          // i = q*16 + idx
        const int q = i >> 4, idx = i & 15, f = idx >> 3, jj = idx & 7;
        const int k = f * 32 + q * 8 + jj;
        w1tb[q][idx] = __builtin_bit_cast(uint, pk(LAM * W1[k], LAM * W1[HID + k]));
    } else if (tid < 192) {
        const int i = tid - 128;
        const int q = i >> 4, idx = i & 15, f = idx >> 3, jj = idx & 7;
        const int k = f * 32 + q * 8 + jj;
        b1tb[q][idx] = LAM * b1[k];
    }
    __syncthreads();

    const float SQ23 = 0.816496580927726f;
    const float si0 = scales_inp[0], si1 = scales_inp[1];
    const float li0 = limits_inp[0], li1 = limits_inp[1];
    const float isg0 = 1.0f / scales_grad[0], isg1 = 1.0f / scales_grad[1];
    const float b30c = b3[0] - limits_grad[0];
    const float b31c = b3[1] - limits_grad[1];
    const float gw  = gp_w[g];

    // ---- held W2 fragments: loaded ONCE, pinned (r5-proven) ----
    uint4 bfq[8];
#pragma unroll
    for (int i = 0; i < 8; i++) bfq[i] = wt[(8 + i) * 64 + lane];
#pragma unroll
    for (int i = 0; i < 8; i++)
        asm volatile("" : "+v"(bfq[i].x), "+v"(bfq[i].y), "+v"(bfq[i].z), "+v"(bfq[i].w));

    // ---- prologue: B + conn + u/Jacc for tile 0 ----
    int T = blockIdx.x * 4 + wv;
    float4 bq0, bq1, bq2, bq3, bq4, bq5;
    {
        const float4* Bp = (const float4*)(B + (size_t)T * 1536 + lane * 24);
        bq0 = Bp[0]; bq1 = Bp[1]; bq2 = Bp[2];
        bq3 = Bp[3]; bq4 = Bp[4]; bq5 = Bp[5];
    }
    int connT = conn[T * 64 + lane];
    float jacT = Jacc[T * 64 + lane];
    float2 uT = *(const float2*)(u + 2 * connT);
    float2 wvT = make_float2(1.f, 1.f);
    if (!premul) wvT = *(const float2*)(weight1 + 2 * connT);

    int connN = 0;
    float2 uN = make_float2(0.f, 0.f), wvN = make_float2(1.f, 1.f);
    float jacN = 0.f;

#pragma unroll 1
    for (; T < NT; T += NWAVE) {
        const int Tn = T + NWAVE;
        const bool hasN = (Tn < NT);
        // prefetch next conn/Jacc (independent loads; land during phase 1)
        if (hasN) {
            connN = conn[Tn * 64 + lane];
            jacN  = Jacc[Tn * 64 + lane];
        }

        // ---- phase 1: strain invariants -> P,Q planes + x ----
        {
            const float vx = wvT.x * uT.x, vy = wvT.y * uT.y;
            float ue[8];
            ue[0] = SWZF(vx, 0x1C); ue[1] = SWZF(vy, 0x1C);
            ue[2] = SWZF(vx, 0x3C); ue[3] = SWZF(vy, 0x3C);
            ue[4] = SWZF(vx, 0x5C); ue[5] = SWZF(vy, 0x5C);
            ue[6] = SWZF(vx, 0x7C); ue[7] = SWZF(vy, 0x7C);

            float Bg[24];
            Bg[0]=bq0.x; Bg[1]=bq0.y; Bg[2]=bq0.z; Bg[3]=bq0.w;
            Bg[4]=bq1.x; Bg[5]=bq1.y; Bg[6]=bq1.z; Bg[7]=bq1.w;
            Bg[8]=bq2.x; Bg[9]=bq2.y; Bg[10]=bq2.z; Bg[11]=bq2.w;
            Bg[12]=bq3.x; Bg[13]=bq3.y; Bg[14]=bq3.z; Bg[15]=bq3.w;
            Bg[16]=bq4.x; Bg[17]=bq4.y; Bg[18]=bq4.z; Bg[19]=bq4.w;
            Bg[20]=bq5.x; Bg[21]=bq5.y; Bg[22]=bq5.z; Bg[23]=bq5.w;

            float s0 = 0.f, s1 = 0.f, s2 = 0.f;
#pragma unroll
            for (int j = 0; j < 8; j++) {
                s0 = fmaf(Bg[j],      ue[j], s0);
                s1 = fmaf(Bg[8 + j],  ue[j], s1);
                s2 = fmaf(Bg[16 + j], ue[j], s2);
            }
            const float ev  = s0 + s1;
            const float ev3 = ev * (1.0f / 3.0f);
            const float d00 = s0 - ev3, d11 = s1 - ev3, d22 = -ev3, d01 = 0.5f * s2;
            const float det = sqrtf(d00 * d00 + d11 * d11 + d22 * d22 + 2.0f * d01 * d01);
            const float rd  = __builtin_amdgcn_rcpf(det);
            const float es  = det * SQ23;
            const float wgt = jacT * gw;
            const float sc  = SQ23 * rd * wgt;
            const float c00 = sc * d00, c11 = sc * d11, c01 = sc * d01;
#pragma unroll
            for (int j = 0; j < 8; j++) {
                const float P = wgt * (Bg[j] + Bg[8 + j]);
                const float Q = fmaf(c00, Bg[j], fmaf(c11, Bg[8 + j], c01 * Bg[16 + j]));
                sPQ[j * 260 + pqb + lane] = __builtin_bit_cast(uint, pk(P, Q));
            }
            sXs[wv][lane] = __builtin_bit_cast(uint,
                pk(fmaf(ev, si0, li0), fmaf(es, si1, li1)));
        }
        // reload B regs for next tile (consumed above; land during phase 2)
        if (hasN) {
            const float4* Bp = (const float4*)(B + (size_t)Tn * 1536 + lane * 24);
            bq0 = Bp[0]; bq1 = Bp[1]; bq2 = Bp[2];
            bq3 = Bp[3]; bq4 = Bp[4]; bq5 = Bp[5];
        }
        asm volatile("s_waitcnt lgkmcnt(0)");
        __builtin_amdgcn_sched_barrier(0);
        // prefetch next u/weight1 (connN landed during phase 1)
        if (hasN) {
            uN = *(const float2*)(u + 2 * connN);
            if (!premul) wvN = *(const float2*)(weight1 + 2 * connN);
        }

        // ---- phase 2: wave-level MFMA MLP over this wave's 64 rows ----
        int zr = 0;                  // opaque zero: keeps table reads in-loop
#pragma unroll 1
        for (int rt = 0; rt < 4; rt++) {
            asm volatile("" : "+v"(zr));
            const int qz = quad + zr;
            const int wb = qz * 16;
            const half2v xp = __builtin_bit_cast(half2v, sXs[wv][rt * 16 + l15]);

            // layer-1 weights: quad-broadcast LDS reads (conflict-free)
            union { uint4 q[4]; uint u[16]; } W1L;
            union { float4 q[4]; float f[16]; } B1L;
#pragma unroll
            for (int i = 0; i < 4; i++) {
                W1L.q[i] = *(const uint4*)&w1tb[qz][4 * i];
                B1L.q[i] = *(const float4*)&b1tb[qz][4 * i];
            }

            union { half8v v; uint uu[4]; } B0, B1;
#pragma unroll
            for (int jj = 0; jj < 4; jj++) {
                const float t0 = tanh2(fdot2(xp, __builtin_bit_cast(half2v, W1L.u[2 * jj]),     B1L.f[2 * jj]));
                const float t1 = tanh2(fdot2(xp, __builtin_bit_cast(half2v, W1L.u[2 * jj + 1]), B1L.f[2 * jj + 1]));
                const float t2 = tanh2(fdot2(xp, __builtin_bit_cast(half2v, W1L.u[8 + 2 * jj]),     B1L.f[8 + 2 * jj]));
                const float t3 = tanh2(fdot2(xp, __builtin_bit_cast(half2v, W1L.u[8 + 2 * jj + 1]), B1L.f[8 + 2 * jj + 1]));
                B0.uu[jj] = __builtin_bit_cast(uint, pk(t0, t1));
                B1.uu[jj] = __builtin_bit_cast(uint, pk(t2, t3));
            }

            half2v sp = {_Float16(0.f), _Float16(0.f)};
            TSTEP(0, bfq[0], bfq[1]);
            TSTEP(1, bfq[2], bfq[3]);
            TSTEP(2, bfq[4], bfq[5]);
            TSTEP(3, bfq[6], bfq[7]);

            float s0 = (float)sp[0], s1 = (float)sp[1];
            s0 += SWZF(s0, 0x401F);
            s1 += SWZF(s1, 0x401F);
            s0 += __shfl_xor(s0, 32, 64);
            s1 += __shfl_xor(s1, 32, 64);
            if (quad == 0) {
                const float p = (s0 + b30c) * isg0;
                const float q = (s1 + b31c) * isg1;
                sGs[wv][rt * 16 + l15] = __builtin_bit_cast(uint, pk(p, q));
            }
        }
        // phase 3 reads only LDS: drain LDS, NOT vmcnt (the compiler will
        // place counted vmcnt waits at phase-1's actual register uses).
        asm volatile("s_waitcnt lgkmcnt(0)");
        __builtin_amdgcn_sched_barrier(0);

        // ---- phase 3: EP pair -> ONE u64 fixed-point atomic per pair ----
        {
            const int rb = lane & ~3;
            const int j0 = 2 * g;
            float a = 0.f, b = 0.f;
#pragma unroll
            for (int gp = 0; gp < 4; gp++) {
                const int rr = rb + gp;
                const half2v pq = __builtin_bit_cast(half2v, sGs[wv][rr]);
                const uint w0 = sPQ[j0 * 260 + pqb + rr];
                const uint w1 = sPQ[(j0 + 1) * 260 + pqb + rr];
                a = fdot2(pq, __builtin_bit_cast(half2v, w0), a);
                b = fdot2(pq, __builtin_bit_cast(half2v, w1), b);
            }
            const int ia = __float2int_rn(a * FSCALE);
            const int ib = __float2int_rn(b * FSCALE);
            const unsigned long long pkd =
                ((unsigned long long)(unsigned)ib << 32) | (unsigned)ia;
            atomicAdd(&F64[connT], pkd);
        }

        connT = connN; uT = uN; jacT = jacN; wvT = wvN;
    }
}

extern "C" void kernel_launch(void* const* d_in, const int* in_sizes, int n_in,
                              void* d_out, int out_size, void* d_ws, size_t ws_size,
                              hipStream_t stream) {
    const float* u           = (const float*)d_in[0];
    const float* B           = (const float*)d_in[1];
    const float* Jacc        = (const float*)d_in[2];
    const float* gp_w        = (const float*)d_in[3];
    const int*   conn        = (const int*)  d_in[4];
    const float* weight1     = (const float*)d_in[5];
    const float* scales_inp  = (const float*)d_in[6];
    const float* limits_inp  = (const float*)d_in[7];
    const float* scales_grad = (const float*)d_in[8];
    const float* limits_grad = (const float*)d_in[9];
    const float* W1          = (const float*)d_in[10];
    const float* b1          = (const float*)d_in[11];
    const float* W2          = (const float*)d_in[12];
    const float* b2          = (const float*)d_in[13];
    const float* W3          = (const float*)d_in[14];
    const float* b3          = (const float*)d_in[15];
    unsigned long long* F64 = (unsigned long long*)d_out;

    uint4* wt = (uint4*)d_ws;                       // 16 KB weight table
    float* u1 = (float*)((char*)d_ws + 16384);      // 2 MB premultiplied u
    const int can_premul = (ws_size >= 16384 + sizeof(float) * NDOF) ? 1 : 0;

    (void)hipMemsetAsync(d_out, 0, sizeof(float) * NDOF, stream);

    setup_all<<<1 + (NDOF / 4 + 255) / 256, 256, 0, stream>>>(
        W2, wt, u, weight1, u1, can_premul);

    fem_force_kernel<<<NBLK, 256, 0, stream>>>(
        can_premul ? u1 : u, B, Jacc, gp_w, conn, weight1,
        scales_inp, limits_inp, scales_grad, limits_grad,
        W1, b1, b2, W3, b3, wt, can_premul, F64);

    convert_F<<<(NNODE + 255) / 256, 256, 0, stream>>>(F64);
}